// Round 1
// 225.114 us; speedup vs baseline: 1.0093x; 1.0093x over previous
//
#include <hip/hip_runtime.h>
#include <math.h>

// Problem constants
#define N_TOK 16384
#define DDIM  2048
#define NE    64
#define TK    8
#define BT    64              // tokens per block tile
#define NBLK  (N_TOK / BT)    // 256 blocks
#define NCHUNK 8              // per half: 8 chunks x 4 steps x 32 K = 1024 K
#define NHC   32              // histogram partial banks

// Scaling keeps fp16 split residues normal; logits scaled by 2^17, unscaled
// exactly in the epilogue.
#define XSCALE 64.0f
#define WSCALE 2048.0f
#define LUNSCALE (1.0f / 131072.0f)

// Output layout (flat concat, all fp32)
constexpr size_t OFF_TOP  = 0;
constexpr size_t OFF_SC   = (size_t)N_TOK * TK;
constexpr size_t OFF_IDX  = OFF_SC + (size_t)N_TOK * NE;
constexpr size_t OFF_HIST = OFF_IDX + (size_t)N_TOK * TK;
constexpr size_t OFF_ENT  = OFF_HIST + NE;

#define WLVL (NE * DDIM)                  // 131072 f16 per split level
#define HISTP_OFF (1u << 20)
#define ENTP_OFF  (HISTP_OFF + NHC * NE * 4)

typedef _Float16 f16x8 __attribute__((ext_vector_type(8)));
typedef float    f32x4 __attribute__((ext_vector_type(4)));

typedef const __attribute__((address_space(1))) unsigned int gu32;
typedef       __attribute__((address_space(3))) unsigned int lu32;

// 2-level fp16 split: v = h + m + r, |r| <= 2^-22 |v|. v - (float)h is exact.
__device__ __forceinline__ void split2(float v, _Float16& h, _Float16& m) {
    h = (_Float16)v;
    m = (_Float16)(v - (float)h);
}

__device__ __forceinline__ unsigned short f16bits(_Float16 h) {
    union { _Float16 f; unsigned short u; } c; c.f = h; return c.u;
}

// ---------------------------------------------------------------------------
// Prep: w*2048 -> 2-level fp16, swizzled B-fragment-linear:
// offset = ((s*4+nt)*64 + lane)*8 + j,  s=k/32, nt=e/16, lane=(k/8%4)*16+e%16
// ---------------------------------------------------------------------------
__global__ __launch_bounds__(64)
void prep_w(const float* __restrict__ w, unsigned short* __restrict__ wre) {
    int gid = blockIdx.x * 64 + threadIdx.x;   // 16384 threads, 8 elems each
    int e  = gid >> 8;
    int kb = gid & 255;
    int k  = kb * 8;
    const float* wp = w + (size_t)e * DDIM + k;
    float4 f0 = *(const float4*)(wp);
    float4 f1 = *(const float4*)(wp + 4);
    float av[8] = {f0.x, f0.y, f0.z, f0.w, f1.x, f1.y, f1.z, f1.w};

    int s = k >> 5, quad = kb & 3, nt = e >> 4, lane = quad * 16 + (e & 15);
    size_t off = ((size_t)(s * 4 + nt) * 64 + lane) * 8;

    unsigned short hb[8], mb[8];
    #pragma unroll
    for (int j = 0; j < 8; ++j) {
        _Float16 h, m;
        split2(av[j] * WSCALE, h, m);
        hb[j] = f16bits(h); mb[j] = f16bits(m);
    }

    #pragma unroll
    for (int lev = 0; lev < 2; ++lev) {
        const unsigned short* src = lev ? mb : hb;
        uint4 v;
        v.x = (unsigned)src[0] | ((unsigned)src[1] << 16);
        v.y = (unsigned)src[2] | ((unsigned)src[3] << 16);
        v.z = (unsigned)src[4] | ((unsigned)src[5] << 16);
        v.w = (unsigned)src[6] | ((unsigned)src[7] << 16);
        *(uint4*)(wre + (size_t)lev * WLVL + off) = v;
    }
}

// ---------------------------------------------------------------------------
// Fused GEMM + epilogue. 256 blocks x 512 threads (8 waves).
// Waves 0-3: tokens wt*16.., K half 0.  Waves 4-7: same tokens, K half 1.
// B double-buffered in LDS (128 KiB), staged ONE CHUNK AHEAD with
// global_load_lds; A prefetched one chunk ahead into registers. One barrier
// per chunk (T3 minimum 2-phase: issue STAGE before compute, never after).
// Halves combined via LDS; sigmoid/top-8/hist/entropy done in-block.
// ---------------------------------------------------------------------------
__global__ __launch_bounds__(512, 2)
void router_fused(const float* __restrict__ x,
                  const unsigned short* __restrict__ wre,
                  const float* __restrict__ bias,
                  float* __restrict__ out,
                  int* __restrict__ histp,
                  float* __restrict__ entp)
{
    union SMem {
        // [half][buf][step-in-chunk][frag = lev*4+nt][lane*8] : 128 KiB
        _Float16 Bs[2][2][4][8][512];
        struct {                      // epilogue overlay (after final barrier)
            float comb[4][64][20];    // wave 4-7 partials, padded stride
            float sct[NE][65];        // scores [expert][token], padded
            float bsh[NE];
            int   hist[NE];
            float entw[4];
        } ep;
    };
    __shared__ SMem sm;

    const int tid  = threadIdx.x;
    const int lane = tid & 63;
    const int wid  = tid >> 6;
    const int wt   = wid & 3;       // token group (16 tokens)
    const int wh   = wid >> 2;      // K half
    const int t0b  = blockIdx.x * BT;
    const int mrow = lane & 15;
    const int quad = lane >> 4;

    const float* xp = x + (size_t)(t0b + wt * 16 + mrow) * DDIM
                        + wh * (DDIM / 2) + quad * 8;

    // Stage chunk c of both halves into buffer nb: 64 rows of 1 KiB,
    // wave wid stages rows wid*8 .. wid*8+7.
    auto stage = [&](int c, int nb) {
        #pragma unroll
        for (int i = 0; i < 8; ++i) {
            const int r  = wid * 8 + i;          // 0..63
            const int h  = r >> 5;
            const int ss = (r >> 3) & 3;
            const int f  = r & 7;
            const int S  = h * 32 + c * 4 + ss;  // global 32-K step 0..63
            const unsigned short* g = wre + (size_t)(f >> 2) * WLVL
                + ((size_t)S * 4 + (f & 3)) * 512 + (size_t)lane * 8;
            __builtin_amdgcn_global_load_lds((gu32*)g,
                (lu32*)&sm.Bs[h][nb][ss][f][0], 16, 0, 0);
        }
    };

    auto loadA = [&](int c, float4 (&A)[8]) {
        #pragma unroll
        for (int ss = 0; ss < 4; ++ss) {
            A[ss * 2]     = *(const float4*)(xp + (c * 4 + ss) * 32);
            A[ss * 2 + 1] = *(const float4*)(xp + (c * 4 + ss) * 32 + 4);
        }
    };

    f32x4 acc[4];
    #pragma unroll
    for (int nt = 0; nt < 4; ++nt) acc[nt] = (f32x4){0.f, 0.f, 0.f, 0.f};

    float4 Aa[8], Ab[8];
    stage(0, 0);
    loadA(0, Aa);
    __syncthreads();                 // drain: B chunk0 + A chunk0 ready

    auto chunk = [&](int c, int cb, float4 (&cur)[8], float4 (&nxt)[8]) {
        if (c + 1 < NCHUNK) {        // issue next-chunk loads BEFORE compute
            stage(c + 1, cb ^ 1);
            loadA(c + 1, nxt);
        }
        #pragma unroll
        for (int ss = 0; ss < 4; ++ss) {
            f16x8 bh[4], bm[4];
            #pragma unroll
            for (int nt = 0; nt < 4; ++nt) {
                bh[nt] = *(const f16x8*)&sm.Bs[wh][cb][ss][nt][lane * 8];
                bm[nt] = *(const f16x8*)&sm.Bs[wh][cb][ss][4 + nt][lane * 8];
            }
            const float4 ca = cur[ss * 2], cb4 = cur[ss * 2 + 1];
            float av[8] = {ca.x, ca.y, ca.z, ca.w, cb4.x, cb4.y, cb4.z, cb4.w};
            f16x8 ah, am;
            #pragma unroll
            for (int j = 0; j < 8; ++j) {
                _Float16 h, m;
                split2(av[j] * XSCALE, h, m);
                ah[j] = h; am[j] = m;
            }
            #pragma unroll
            for (int nt = 0; nt < 4; ++nt) {
                acc[nt] = __builtin_amdgcn_mfma_f32_16x16x32_f16(ah, bh[nt], acc[nt], 0, 0, 0);
                acc[nt] = __builtin_amdgcn_mfma_f32_16x16x32_f16(am, bh[nt], acc[nt], 0, 0, 0);
                acc[nt] = __builtin_amdgcn_mfma_f32_16x16x32_f16(ah, bm[nt], acc[nt], 0, 0, 0);
                acc[nt] = __builtin_amdgcn_mfma_f32_16x16x32_f16(am, bm[nt], acc[nt], 0, 0, 0);
            }
        }
        __syncthreads();             // one drain per chunk; next buffer ready
    };

    #pragma unroll
    for (int c2 = 0; c2 < NCHUNK / 2; ++c2) {
        chunk(2 * c2,     0, Aa, Ab);
        chunk(2 * c2 + 1, 1, Ab, Aa);
    }

    // ---- epilogue (Bs dead; overlay union) ----
    if (tid < NE) { sm.ep.bsh[tid] = bias[tid]; sm.ep.hist[tid] = 0; }
    if (wh == 1) {
        #pragma unroll
        for (int nt = 0; nt < 4; ++nt)
            *(f32x4*)&sm.ep.comb[wt][lane][nt * 4] = acc[nt];
    }
    __syncthreads();

    if (wh == 0) {
        #pragma unroll
        for (int nt = 0; nt < 4; ++nt) {
            f32x4 o = *(const f32x4*)&sm.ep.comb[wt][lane][nt * 4];
            f32x4 s = acc[nt] + o;
            const int e = nt * 16 + mrow;       // C/D: col=lane&15 -> expert
            #pragma unroll
            for (int r = 0; r < 4; ++r) {
                const int tl = wt * 16 + quad * 4 + r;  // row -> token
                const float sg = 1.0f / (1.0f + expf(-s[r] * LUNSCALE));
                sm.ep.sct[e][tl] = sg;
                out[OFF_SC + (size_t)(t0b + tl) * NE + e] = sg;
            }
        }
    }
    __syncthreads();

    // Top-8: waves 0-3, lane = quad-expert-group x 16 tokens.
    float entv = 0.f;
    if (wh == 0) {
        const int tl = wt * 16 + mrow;
        const int eg = quad;                    // expert group of 16
        float v[16];
        #pragma unroll
        for (int i = 0; i < 16; ++i)
            v[i] = sm.ep.sct[eg * 16 + i][tl] + sm.ep.bsh[eg * 16 + i];

        float ch[TK]; int ci[TK]; float ssum = 0.f;
        #pragma unroll
        for (int p = 0; p < TK; ++p) {
            float bv = v[0]; int bi = 0;
            #pragma unroll
            for (int i = 1; i < 16; ++i) {      // strict '>': lowest idx on tie
                const bool sgt = v[i] > bv;
                bv = sgt ? v[i] : bv;
                bi = sgt ? i : bi;
            }
            int be = eg * 16 + bi;
            {   // combine groups: lane^16 (same token, other group)
                float ov = __shfl_xor(bv, 16);
                int   oe = __shfl_xor(be, 16);
                const bool tk = (ov > bv) || (ov == bv && oe < be);
                bv = tk ? ov : bv; be = tk ? oe : be;
            }
            {   // lane^32
                float ov = __shfl_xor(bv, 32);
                int   oe = __shfl_xor(be, 32);
                const bool tk = (ov > bv) || (ov == bv && oe < be);
                bv = tk ? ov : bv; be = tk ? oe : be;
            }
            #pragma unroll
            for (int i = 0; i < 16; ++i)        // static-index mask (rule #20)
                v[i] = (be == eg * 16 + i) ? -1e30f : v[i];
            const float sc = sm.ep.sct[be][tl]; // unbiased score
            ch[p] = sc; ci[p] = be; ssum += sc;
        }
        if (eg == 0) {
            const float inv = 1.0f / (ssum + 1e-20f);
            #pragma unroll
            for (int p = 0; p < TK; ++p) {
                atomicAdd(&sm.ep.hist[ci[p]], 1);
                const float pn = ch[p] * inv;   // ROUTE_SCALE == 1.0
                out[OFF_TOP + (size_t)(t0b + tl) * TK + p] = pn;
                out[OFF_IDX + (size_t)(t0b + tl) * TK + p] = (float)ci[p];
                entv += pn * logf(pn);
            }
        }
        entv += __shfl_down(entv, 8);
        entv += __shfl_down(entv, 4);
        entv += __shfl_down(entv, 2);
        entv += __shfl_down(entv, 1);
        if (lane == 0) sm.ep.entw[wid] = entv;
    }
    __syncthreads();

    if (tid == 0)
        entp[blockIdx.x] = sm.ep.entw[0] + sm.ep.entw[1]
                         + sm.ep.entw[2] + sm.ep.entw[3];
    if (tid < NE && sm.ep.hist[tid] > 0)
        atomicAdd(&histp[(blockIdx.x & (NHC - 1)) * NE + tid], sm.ep.hist[tid]);
}

// ---------------------------------------------------------------------------
// Finalize: reduce histogram banks and entropy partials (deterministic)
// ---------------------------------------------------------------------------
__global__ __launch_bounds__(256)
void finalize(const int* __restrict__ histp,
              const float* __restrict__ entp,
              float* __restrict__ out)
{
    const int tid = threadIdx.x;
    if (tid < NE) {
        int s = 0;
        #pragma unroll
        for (int c = 0; c < NHC; ++c) s += histp[c * NE + tid];
        out[OFF_HIST + tid] = (float)s;
    }
    __shared__ float red[256];
    float e = 0.f;
    for (int i = tid; i < NBLK; i += 256) e += entp[i];
    red[tid] = e;
    __syncthreads();
    #pragma unroll
    for (int o = 128; o > 0; o >>= 1) {
        if (tid < o) red[tid] += red[tid + o];
        __syncthreads();
    }
    if (tid == 0) out[OFF_ENT] = -red[0] * (1.0f / (float)N_TOK);
}

extern "C" void kernel_launch(void* const* d_in, const int* in_sizes, int n_in,
                              void* d_out, int out_size, void* d_ws, size_t ws_size,
                              hipStream_t stream) {
    const float* x    = (const float*)d_in[0];   // [16384, 2048]
    const float* w    = (const float*)d_in[1];   // [64, 2048]
    const float* bias = (const float*)d_in[2];   // [64]
    float* out = (float*)d_out;
    unsigned short* wre = (unsigned short*)d_ws;            // 512 KB (2 levels)
    int*   histp = (int*)  ((char*)d_ws + HISTP_OFF);
    float* entp  = (float*)((char*)d_ws + ENTP_OFF);

    hipMemsetAsync(histp, 0, NHC * NE * sizeof(int), stream);

    prep_w      <<<dim3(256),  dim3(64),  0, stream>>>(w, wre);
    router_fused<<<dim3(NBLK), dim3(512), 0, stream>>>(x, wre, bias, out, histp, entp);
    finalize    <<<dim3(1),    dim3(256), 0, stream>>>(histp, entp, out);
}

// Round 2
// 221.566 us; speedup vs baseline: 1.0254x; 1.0160x over previous
//
#include <hip/hip_runtime.h>
#include <math.h>

// Problem constants
#define N_TOK 16384
#define DDIM  2048
#define NE    64
#define TK    8
#define BT    64              // tokens per block tile
#define NBLK  (N_TOK / BT)    // 256 blocks
#define NCHUNK 8              // per half: 8 chunks x 4 steps x 32 K = 1024 K
#define NHC   32              // histogram partial banks

// Scaling keeps fp16 split residues normal; logits scaled by 2^17, unscaled
// exactly in the epilogue.
#define XSCALE 64.0f
#define WSCALE 2048.0f
#define LUNSCALE (1.0f / 131072.0f)

// Output layout (flat concat, all fp32)
constexpr size_t OFF_TOP  = 0;
constexpr size_t OFF_SC   = (size_t)N_TOK * TK;
constexpr size_t OFF_IDX  = OFF_SC + (size_t)N_TOK * NE;
constexpr size_t OFF_HIST = OFF_IDX + (size_t)N_TOK * TK;
constexpr size_t OFF_ENT  = OFF_HIST + NE;

#define WLVL (NE * DDIM)                  // 131072 f16 per split level
#define HISTP_OFF (1u << 20)
#define ENTP_OFF  (HISTP_OFF + NHC * NE * 4)

typedef _Float16 f16x8 __attribute__((ext_vector_type(8)));
typedef float    f32x4 __attribute__((ext_vector_type(4)));

// 2-level fp16 split: v = h + m + r, |r| <= 2^-22 |v|. v - (float)h is exact.
__device__ __forceinline__ void split2(float v, _Float16& h, _Float16& m) {
    h = (_Float16)v;
    m = (_Float16)(v - (float)h);
}

__device__ __forceinline__ unsigned short f16bits(_Float16 h) {
    union { _Float16 f; unsigned short u; } c; c.f = h; return c.u;
}

// ---------------------------------------------------------------------------
// Prep: w*2048 -> 2-level fp16, swizzled B-fragment-linear:
// offset = ((s*4+nt)*64 + lane)*8 + j,  s=k/32, nt=e/16, lane=(k/8%4)*16+e%16
// ---------------------------------------------------------------------------
__global__ __launch_bounds__(64)
void prep_w(const float* __restrict__ w, unsigned short* __restrict__ wre) {
    int gid = blockIdx.x * 64 + threadIdx.x;   // 16384 threads, 8 elems each
    int e  = gid >> 8;
    int kb = gid & 255;
    int k  = kb * 8;
    const float* wp = w + (size_t)e * DDIM + k;
    float4 f0 = *(const float4*)(wp);
    float4 f1 = *(const float4*)(wp + 4);
    float av[8] = {f0.x, f0.y, f0.z, f0.w, f1.x, f1.y, f1.z, f1.w};

    int s = k >> 5, quad = kb & 3, nt = e >> 4, lane = quad * 16 + (e & 15);
    size_t off = ((size_t)(s * 4 + nt) * 64 + lane) * 8;

    unsigned short hb[8], mb[8];
    #pragma unroll
    for (int j = 0; j < 8; ++j) {
        _Float16 h, m;
        split2(av[j] * WSCALE, h, m);
        hb[j] = f16bits(h); mb[j] = f16bits(m);
    }

    #pragma unroll
    for (int lev = 0; lev < 2; ++lev) {
        const unsigned short* src = lev ? mb : hb;
        uint4 v;
        v.x = (unsigned)src[0] | ((unsigned)src[1] << 16);
        v.y = (unsigned)src[2] | ((unsigned)src[3] << 16);
        v.z = (unsigned)src[4] | ((unsigned)src[5] << 16);
        v.w = (unsigned)src[6] | ((unsigned)src[7] << 16);
        *(uint4*)(wre + (size_t)lev * WLVL + off) = v;
    }
}

// ---------------------------------------------------------------------------
// Fused GEMM + epilogue, ZERO-LDS main loop. 256 blocks x 512 threads.
// Waves 0-3: tokens wt*16.., K half 0.  Waves 4-7: same tokens, K half 1.
// B fragments are loaded straight from global (fragment-linear wre, coalesced
// 1KB/instr, L2-broadcast-resident) into registers, depth-1 prefetch; A is a
// 4-step register ring, depth-1 chunk prefetch. NO barriers until the
// epilogue -> waves run free, no vmcnt(0) convoy, no LDS bandwidth ceiling.
// ---------------------------------------------------------------------------
__global__ __launch_bounds__(512, 2)
void router_fused(const float* __restrict__ x,
                  const unsigned short* __restrict__ wre,
                  const float* __restrict__ bias,
                  float* __restrict__ out,
                  int* __restrict__ histp,
                  float* __restrict__ entp)
{
    __shared__ struct {
        float comb[4][64][20];    // wave 4-7 partials, padded stride
        float sct[NE][65];        // scores [expert][token], padded
        float bsh[NE];
        int   hist[NE];
        float entw[4];
    } sm;                          // ~38 KB

    const int tid  = threadIdx.x;
    const int lane = tid & 63;
    const int wid  = tid >> 6;
    const int wt   = wid & 3;       // token group (16 tokens)
    const int wh   = wid >> 2;      // K half
    const int t0b  = blockIdx.x * BT;
    const int mrow = lane & 15;
    const int quad = lane >> 4;
    const int S0   = wh * 32;       // first global 32-K step of this half

    const float* xp = x + (size_t)(t0b + wt * 16 + mrow) * DDIM
                        + wh * (DDIM / 2) + quad * 8;
    const unsigned short* wl = wre + (size_t)lane * 8;

    f32x4 acc[4];
    #pragma unroll
    for (int nt = 0; nt < 4; ++nt) acc[nt] = (f32x4){0.f, 0.f, 0.f, 0.f};

    float4 Aa[8], Ab[8];
    f16x8  B0[8], B1[8];

    auto loadA = [&](int c, float4 (&A)[8]) {
        #pragma unroll
        for (int ss = 0; ss < 4; ++ss) {
            A[ss * 2]     = *(const float4*)(xp + (c * 4 + ss) * 32);
            A[ss * 2 + 1] = *(const float4*)(xp + (c * 4 + ss) * 32 + 4);
        }
    };
    // B fragments for global step S, straight from fragment-linear wre.
    auto loadB = [&](int S, f16x8 (&B)[8]) {
        #pragma unroll
        for (int f = 0; f < 8; ++f)
            B[f] = *(const f16x8*)(wl + (size_t)(f >> 2) * WLVL
                                      + ((size_t)(S * 4 + (f & 3)) << 9));
    };
    auto compute = [&](const float4 ca, const float4 cb4, f16x8 (&B)[8]) {
        float av[8] = {ca.x, ca.y, ca.z, ca.w, cb4.x, cb4.y, cb4.z, cb4.w};
        f16x8 ah, am;
        #pragma unroll
        for (int j = 0; j < 8; ++j) {
            _Float16 h, m;
            split2(av[j] * XSCALE, h, m);
            ah[j] = h; am[j] = m;
        }
        #pragma unroll
        for (int nt = 0; nt < 4; ++nt) {
            acc[nt] = __builtin_amdgcn_mfma_f32_16x16x32_f16(ah, B[nt],     acc[nt], 0, 0, 0);
            acc[nt] = __builtin_amdgcn_mfma_f32_16x16x32_f16(am, B[nt],     acc[nt], 0, 0, 0);
            acc[nt] = __builtin_amdgcn_mfma_f32_16x16x32_f16(ah, B[4 + nt], acc[nt], 0, 0, 0);
            acc[nt] = __builtin_amdgcn_mfma_f32_16x16x32_f16(am, B[4 + nt], acc[nt], 0, 0, 0);
        }
    };

    loadA(0, Aa);
    loadB(S0, B0);

    // B ping-pong parity resets every chunk (4 steps); A ping-pong via
    // explicit pairing (all indices static -> registers, rule #20).
    auto chunk = [&](int c, float4 (&cur)[8], float4 (&nxt)[8]) {
        if (c + 1 < NCHUNK) loadA(c + 1, nxt);
        #pragma unroll
        for (int sp = 0; sp < 2; ++sp) {
            const int s0 = c * 4 + sp * 2;
            loadB(S0 + (s0 + 1 < 32 ? s0 + 1 : 31), B1);  // clamp: dead load
            compute(cur[sp * 4 + 0], cur[sp * 4 + 1], B0);
            loadB(S0 + (s0 + 2 < 32 ? s0 + 2 : 31), B0);
            compute(cur[sp * 4 + 2], cur[sp * 4 + 3], B1);
        }
    };

    for (int c2 = 0; c2 < NCHUNK / 2; ++c2) {
        chunk(2 * c2,     Aa, Ab);
        chunk(2 * c2 + 1, Ab, Aa);
    }

    // ---- epilogue ----
    if (tid < NE) { sm.bsh[tid] = bias[tid]; sm.hist[tid] = 0; }
    if (wh == 1) {
        #pragma unroll
        for (int nt = 0; nt < 4; ++nt)
            *(f32x4*)&sm.comb[wt][lane][nt * 4] = acc[nt];
    }
    __syncthreads();

    if (wh == 0) {
        #pragma unroll
        for (int nt = 0; nt < 4; ++nt) {
            f32x4 o = *(const f32x4*)&sm.comb[wt][lane][nt * 4];
            f32x4 s = acc[nt] + o;
            const int e = nt * 16 + mrow;       // C/D: col=lane&15 -> expert
            #pragma unroll
            for (int r = 0; r < 4; ++r) {
                const int tl = wt * 16 + quad * 4 + r;  // row -> token
                sm.sct[e][tl] = 1.0f / (1.0f + expf(-s[r] * LUNSCALE));
            }
        }
    }
    __syncthreads();

    float entv = 0.f;
    if (wh == 0) {
        // Top-8: lane = expert-group(quad) x 16 tokens.
        const int tl = wt * 16 + mrow;
        const int eg = quad;                    // expert group of 16
        float v[16];
        #pragma unroll
        for (int i = 0; i < 16; ++i)
            v[i] = sm.sct[eg * 16 + i][tl] + sm.bsh[eg * 16 + i];

        float ch[TK]; int ci[TK]; float ssum = 0.f;
        #pragma unroll
        for (int p = 0; p < TK; ++p) {
            float bv = v[0]; int bi = 0;
            #pragma unroll
            for (int i = 1; i < 16; ++i) {      // strict '>': lowest idx on tie
                const bool sgt = v[i] > bv;
                bv = sgt ? v[i] : bv;
                bi = sgt ? i : bi;
            }
            int be = eg * 16 + bi;
            {   // combine groups: lane^16 (same token, other group)
                float ov = __shfl_xor(bv, 16);
                int   oe = __shfl_xor(be, 16);
                const bool tk = (ov > bv) || (ov == bv && oe < be);
                bv = tk ? ov : bv; be = tk ? oe : be;
            }
            {   // lane^32
                float ov = __shfl_xor(bv, 32);
                int   oe = __shfl_xor(be, 32);
                const bool tk = (ov > bv) || (ov == bv && oe < be);
                bv = tk ? ov : bv; be = tk ? oe : be;
            }
            #pragma unroll
            for (int i = 0; i < 16; ++i)        // static-index mask (rule #20)
                v[i] = (be == eg * 16 + i) ? -1e30f : v[i];
            const float sc = sm.sct[be][tl];    // unbiased score
            ch[p] = sc; ci[p] = be; ssum += sc;
        }
        if (eg == 0) {
            const float inv = 1.0f / (ssum + 1e-20f);
            #pragma unroll
            for (int p = 0; p < TK; ++p) {
                atomicAdd(&sm.hist[ci[p]], 1);
                const float pn = ch[p] * inv;   // ROUTE_SCALE == 1.0
                out[OFF_TOP + (size_t)(t0b + tl) * TK + p] = pn;
                out[OFF_IDX + (size_t)(t0b + tl) * TK + p] = (float)ci[p];
                entv += pn * logf(pn);
            }
        }
        entv += __shfl_down(entv, 8);
        entv += __shfl_down(entv, 4);
        entv += __shfl_down(entv, 2);
        entv += __shfl_down(entv, 1);
        if (lane == 0) sm.entw[wid] = entv;
    } else {
        // Waves 4-7 (otherwise idle): coalesced float4 score store from LDS.
        const int t  = (wid - 4) * 16 + (lane >> 2);
        const int e0 = (lane & 3) * 16;
        #pragma unroll
        for (int g = 0; g < 4; ++g) {
            float4 v;
            v.x = sm.sct[e0 + g * 4 + 0][t];
            v.y = sm.sct[e0 + g * 4 + 1][t];
            v.z = sm.sct[e0 + g * 4 + 2][t];
            v.w = sm.sct[e0 + g * 4 + 3][t];
            *(float4*)&out[OFF_SC + (size_t)(t0b + t) * NE + e0 + g * 4] = v;
        }
    }
    __syncthreads();

    if (tid == 0)
        entp[blockIdx.x] = sm.entw[0] + sm.entw[1] + sm.entw[2] + sm.entw[3];
    if (tid < NE && sm.hist[tid] > 0)
        atomicAdd(&histp[(blockIdx.x & (NHC - 1)) * NE + tid], sm.hist[tid]);
}

// ---------------------------------------------------------------------------
// Finalize: reduce histogram banks and entropy partials (deterministic)
// ---------------------------------------------------------------------------
__global__ __launch_bounds__(256)
void finalize(const int* __restrict__ histp,
              const float* __restrict__ entp,
              float* __restrict__ out)
{
    const int tid = threadIdx.x;
    if (tid < NE) {
        int s = 0;
        #pragma unroll
        for (int c = 0; c < NHC; ++c) s += histp[c * NE + tid];
        out[OFF_HIST + tid] = (float)s;
    }
    __shared__ float red[256];
    float e = 0.f;
    for (int i = tid; i < NBLK; i += 256) e += entp[i];
    red[tid] = e;
    __syncthreads();
    #pragma unroll
    for (int o = 128; o > 0; o >>= 1) {
        if (tid < o) red[tid] += red[tid + o];
        __syncthreads();
    }
    if (tid == 0) out[OFF_ENT] = -red[0] * (1.0f / (float)N_TOK);
}

extern "C" void kernel_launch(void* const* d_in, const int* in_sizes, int n_in,
                              void* d_out, int out_size, void* d_ws, size_t ws_size,
                              hipStream_t stream) {
    const float* x    = (const float*)d_in[0];   // [16384, 2048]
    const float* w    = (const float*)d_in[1];   // [64, 2048]
    const float* bias = (const float*)d_in[2];   // [64]
    float* out = (float*)d_out;
    unsigned short* wre = (unsigned short*)d_ws;            // 512 KB (2 levels)
    int*   histp = (int*)  ((char*)d_ws + HISTP_OFF);
    float* entp  = (float*)((char*)d_ws + ENTP_OFF);

    hipMemsetAsync(histp, 0, NHC * NE * sizeof(int), stream);

    prep_w      <<<dim3(256),  dim3(64),  0, stream>>>(w, wre);
    router_fused<<<dim3(NBLK), dim3(512), 0, stream>>>(x, wre, bias, out, histp, entp);
    finalize    <<<dim3(1),    dim3(256), 0, stream>>>(histp, entp, out);
}